// Round 8
// baseline (574.548 us; speedup 1.0000x reference)
//
#include <hip/hip_runtime.h>
#include <stdint.h>

// Bahdanau attention: B=64, T=2048, D=256, U=256, all fp32 in/out.
// out = [context (B*D) | attn (B*T)] flat fp32.
#define Bq 64
#define Tq 2048
#define Dq 256
#define Uq 256

typedef __bf16 bf16x8 __attribute__((ext_vector_type(8)));
typedef float f32x4 __attribute__((ext_vector_type(4)));

// LDS tile geometry (A and B identical): [plane][k-oct 0..3][row 0..255][16B]
// oct stride = 256*16 + 32 pad = 4128 B  (4128/16 = 258 ≡ 2 mod 8 -> bank-uniform)
#define OST 4128
#define PST (4 * OST)   // plane stride 16512
#define TILESZ (2 * PST)

// split fp32 into truncated-bf16 hi + bf16(lo) residual. a = hi + lo + O(2^-16 |a|)
__device__ inline void split2(float a, unsigned short& h, unsigned short& l) {
  unsigned bits = __float_as_uint(a);
  h = (unsigned short)(bits >> 16);
  float hf = __uint_as_float(bits & 0xffff0000u);
  l = (unsigned short)(__float_as_uint(a - hf) >> 16);
}

// tanh(x) = 1 - 2/(exp(2x)+1). ~6 VALU ops, saturates correctly.
__device__ inline float fast_tanh(float x) {
  float e = __expf(2.0f * x);
  return 1.0f - 2.0f * __builtin_amdgcn_rcpf(e + 1.0f);
}

// K0: split w1 [U][D] fp32 -> bf16 hi/lo planes, stored OCTET-MAJOR:
// plane[(k>>3)*U*8 + u*8 + (k&7)]
__global__ void k0_split(const float* __restrict__ w1,
                         unsigned short* __restrict__ hi,
                         unsigned short* __restrict__ lo) {
  int idx = blockIdx.x * 256 + threadIdx.x;
  int i = idx * 4;
  int u = i >> 8;
  int k = i & 255;
  float4 v = *reinterpret_cast<const float4*>(&w1[i]);
  ushort4 h, l;
  split2(v.x, h.x, l.x);
  split2(v.y, h.y, l.y);
  split2(v.z, h.z, l.z);
  split2(v.w, h.w, l.w);
  int dst = (k >> 3) * (Uq * 8) + u * 8 + (k & 7);
  *reinterpret_cast<ushort4*>(&hi[dst]) = h;
  *reinterpret_cast<ushort4*>(&lo[dst]) = l;
}

// K1: comb[b][u] = dot(hidden[b], w2_w[u]) + w2_b[u] + w1_b[u]
__global__ void k1_comb(const float* __restrict__ hidden,
                        const float* __restrict__ w2_w,
                        const float* __restrict__ w2_b,
                        const float* __restrict__ w1_b,
                        float* __restrict__ comb) {
  int b = blockIdx.x;
  int wave = threadIdx.x >> 6;
  int lane = threadIdx.x & 63;
  int u = blockIdx.y * 4 + wave;
  const float* h = hidden + b * Dq;
  const float* w = w2_w + u * Dq;
  float sum = 0.f;
#pragma unroll
  for (int i = 0; i < Dq; i += 64) sum += h[lane + i] * w[lane + i];
#pragma unroll
  for (int m = 32; m >= 1; m >>= 1) sum += __shfl_xor(sum, m, 64);
  if (lane == 0) comb[b * Uq + u] = sum + w2_b[u] + w1_b[u];
}

// K2: score[b][t] = v_b + sum_u v_w[u] * tanh( feat[b,t,:]·w1_w[u,:] + comb[b][u] )
// MFMA 16x16x32 bf16, 3-plane split precision.
// Block = 1024 thr = 16 waves (4x4); tile 256t x 256u; wave tile 64x64.
// Grid = 512 blocks = exactly 2 resident per CU -> 32 waves/CU (8/SIMD max).
// Per K-chunk(32): B DMA'd to LDS (32 x 1KB global_load_lds), A loaded/split/
// written by all 1024 threads; 2 barriers per chunk; inter-block TLP hides all.
__global__ __launch_bounds__(1024, 8) void k2_score(
    const float* __restrict__ feat, const unsigned short* __restrict__ w1hi,
    const unsigned short* __restrict__ w1lo, const float* __restrict__ comb,
    const float* __restrict__ v_w, const float* __restrict__ v_b,
    float* __restrict__ score) {
  __shared__ char sA[TILESZ];
  __shared__ char sB[TILESZ];
  __shared__ float scp[4][256];
  const int tid = threadIdx.x;
  const int w = tid >> 6;
  const int l = tid & 63;
  const int fr = l & 15;
  const int g = l >> 4;
  const int wr = w >> 2;
  const int wc = w & 3;
  const int r0 = blockIdx.x * 256;  // flat (b,t) row base

  // A staging role: row = tid>>2 (0..255), oct = tid&3; 8 floats per thread
  const int arow = tid >> 2;
  const int aoct = tid & 3;
  const float* aload = feat + (size_t)(r0 + arow) * Dq + aoct * 8;
  char* const awr_ = sA + aoct * OST + arow * 16;

  f32x4 acc[4][4] = {};

  for (int c = 0; c < 8; ++c) {
    const int kc = c * 32;
    // ---- B: 32 x 1KB DMA, wave w issues d = 2w, 2w+1 ----
#pragma unroll
    for (int q = 0; q < 2; ++q) {
      int d = w * 2 + q;               // 0..31
      int p = d >> 4;                  // plane
      int j = (d >> 2) & 3;            // k-octet within chunk
      int h2 = d & 3;                  // u quarter (64 u)
      const unsigned short* src = (p ? w1lo : w1hi) +
          (size_t)(c * 4 + j) * (Uq * 8) + (h2 * 64 + l) * 8;
      char* dst = sB + p * PST + j * OST + h2 * 1024;
      __builtin_amdgcn_global_load_lds(
          (const __attribute__((address_space(1))) unsigned int*)src,
          (__attribute__((address_space(3))) unsigned int*)dst, 16, 0, 0);
    }
    // ---- A: load 8 floats, split, write hi+lo (conflict-uniform layout) ----
    {
      float4 v0 = *reinterpret_cast<const float4*>(aload + kc);
      float4 v1 = *reinterpret_cast<const float4*>(aload + kc + 4);
      float f[8] = {v0.x, v0.y, v0.z, v0.w, v1.x, v1.y, v1.z, v1.w};
      unsigned short h[8], lo8[8];
#pragma unroll
      for (int j = 0; j < 8; ++j) split2(f[j], h[j], lo8[j]);
      uint4 H, L;
      H.x = h[0] | (h[1] << 16);     H.y = h[2] | (h[3] << 16);
      H.z = h[4] | (h[5] << 16);     H.w = h[6] | (h[7] << 16);
      L.x = lo8[0] | (lo8[1] << 16); L.y = lo8[2] | (lo8[3] << 16);
      L.z = lo8[4] | (lo8[5] << 16); L.w = lo8[6] | (lo8[7] << 16);
      *reinterpret_cast<uint4*>(awr_) = H;
      *reinterpret_cast<uint4*>(awr_ + PST) = L;
    }
    __syncthreads();
    // ---- fragments ----
    bf16x8 ahv[4], alv[4], bhv[4], blv[4];
#pragma unroll
    for (int mf = 0; mf < 4; ++mf) {
      const char* r = sA + g * OST + (wr * 64 + mf * 16 + fr) * 16;
      ahv[mf] = *reinterpret_cast<const bf16x8*>(r);
      alv[mf] = *reinterpret_cast<const bf16x8*>(r + PST);
    }
#pragma unroll
    for (int nf = 0; nf < 4; ++nf) {
      const char* r = sB + g * OST + (wc * 64 + nf * 16 + fr) * 16;
      bhv[nf] = *reinterpret_cast<const bf16x8*>(r);
      blv[nf] = *reinterpret_cast<const bf16x8*>(r + PST);
    }
    // ---- 3-plane MFMA ----
#pragma unroll
    for (int mf = 0; mf < 4; ++mf) {
#pragma unroll
      for (int nf = 0; nf < 4; ++nf) {
        acc[mf][nf] = __builtin_amdgcn_mfma_f32_16x16x32_bf16(
            ahv[mf], bhv[nf], acc[mf][nf], 0, 0, 0);
        acc[mf][nf] = __builtin_amdgcn_mfma_f32_16x16x32_bf16(
            ahv[mf], blv[nf], acc[mf][nf], 0, 0, 0);
        acc[mf][nf] = __builtin_amdgcn_mfma_f32_16x16x32_bf16(
            alv[mf], bhv[nf], acc[mf][nf], 0, 0, 0);
      }
    }
    __syncthreads();
  }

  // ---- epilogue: tanh + v-dot. acc[mf][nf][r] is
  // (t_local = wr*64 + mf*16 + g*4 + r, u = wc*64 + nf*16 + fr) ----
  const int b = r0 >> 11;  // /Tq
  float cb[4], vw4[4];
#pragma unroll
  for (int nf = 0; nf < 4; ++nf) {
    int u = wc * 64 + nf * 16 + fr;
    cb[nf] = comb[b * Uq + u];
    vw4[nf] = v_w[u];
  }
  float sc[4][4];
#pragma unroll
  for (int mf = 0; mf < 4; ++mf)
#pragma unroll
    for (int r = 0; r < 4; ++r) sc[mf][r] = 0.f;
#pragma unroll
  for (int mf = 0; mf < 4; ++mf)
#pragma unroll
    for (int nf = 0; nf < 4; ++nf)
#pragma unroll
      for (int r = 0; r < 4; ++r)
        sc[mf][r] += vw4[nf] * fast_tanh(acc[mf][nf][r] + cb[nf]);
  // reduce over 16 fr lanes
#pragma unroll
  for (int m = 1; m < 16; m <<= 1)
#pragma unroll
    for (int mf = 0; mf < 4; ++mf)
#pragma unroll
      for (int r = 0; r < 4; ++r) sc[mf][r] += __shfl_xor(sc[mf][r], m, 16);
  if (fr == 0) {
#pragma unroll
    for (int mf = 0; mf < 4; ++mf)
#pragma unroll
      for (int r = 0; r < 4; ++r)
        scp[wc][wr * 64 + mf * 16 + g * 4 + r] = sc[mf][r];
  }
  __syncthreads();
  if (tid < 256)
    score[r0 + tid] =
        scp[0][tid] + scp[1][tid] + scp[2][tid] + scp[3][tid] + v_b[0];
}

// K3: softmax over T per batch, in place. 256 threads, 8 values each.
__global__ void k3_softmax(float* __restrict__ s) {
  int b = blockIdx.x;
  int tid = threadIdx.x;
  const int base = b * Tq;
  float v[8];
  float m = -1e30f;
#pragma unroll
  for (int i = 0; i < 8; ++i) {
    v[i] = s[base + tid + 256 * i];
    m = fmaxf(m, v[i]);
  }
#pragma unroll
  for (int mk = 32; mk >= 1; mk >>= 1) m = fmaxf(m, __shfl_xor(m, mk, 64));
  __shared__ float red[4];
  int wv = tid >> 6, ln = tid & 63;
  if (ln == 0) red[wv] = m;
  __syncthreads();
  m = fmaxf(fmaxf(red[0], red[1]), fmaxf(red[2], red[3]));
  __syncthreads();
  float sum = 0.f;
#pragma unroll
  for (int i = 0; i < 8; ++i) {
    v[i] = __expf(v[i] - m);
    sum += v[i];
  }
#pragma unroll
  for (int mk = 32; mk >= 1; mk >>= 1) sum += __shfl_xor(sum, mk, 64);
  if (ln == 0) red[wv] = sum;
  __syncthreads();
  sum = red[0] + red[1] + red[2] + red[3];
  float inv = 1.f / sum;
#pragma unroll
  for (int i = 0; i < 8; ++i) s[base + tid + 256 * i] = v[i] * inv;
}

// K4a: partial context over a 256-t slice
__global__ void k4_partial(const float* __restrict__ feat,
                           const float* __restrict__ attn,
                           float* __restrict__ part) {
  int b = blockIdx.x;
  int ts = blockIdx.y;
  int d = threadIdx.x;
  const int t0 = ts * 256;
  const float* f = feat + ((size_t)(b * Tq + t0)) * Dq + d;
  const float* a = attn + b * Tq + t0;
  float acc = 0.f;
#pragma unroll 8
  for (int t = 0; t < 256; ++t) acc += a[t] * f[(size_t)t * Dq];
  part[(b * 8 + ts) * Dq + d] = acc;
}

// K4b: reduce the 8 partials
__global__ void k4_reduce(const float* __restrict__ part,
                          float* __restrict__ ctx) {
  int b = blockIdx.x;
  int d = threadIdx.x;
  float s = 0.f;
#pragma unroll
  for (int ts = 0; ts < 8; ++ts) s += part[(b * 8 + ts) * Dq + d];
  ctx[b * Dq + d] = s;
}

extern "C" void kernel_launch(void* const* d_in, const int* in_sizes, int n_in,
                              void* d_out, int out_size, void* d_ws,
                              size_t ws_size, hipStream_t stream) {
  const float* feat   = (const float*)d_in[0];
  const float* hidden = (const float*)d_in[1];
  const float* w1_w   = (const float*)d_in[2];
  const float* w1_b   = (const float*)d_in[3];
  const float* w2_w   = (const float*)d_in[4];
  const float* w2_b   = (const float*)d_in[5];
  const float* v_w    = (const float*)d_in[6];
  const float* v_b    = (const float*)d_in[7];

  float* ctx  = (float*)d_out;             // [B][D]
  float* attn = ctx + Bq * Dq;             // [B][T] (score -> softmax in place)
  float* comb = (float*)d_ws;              // [B][U]        64 KB
  float* part = comb + Bq * Uq;            // [B][8][D]     512 KB
  unsigned short* w1hi = (unsigned short*)(part + Bq * 8 * Dq);  // 128 KB
  unsigned short* w1lo = w1hi + Uq * Dq;                          // 128 KB

  k0_split<<<Uq * Dq / 1024, 256, 0, stream>>>(w1_w, w1hi, w1lo);
  k1_comb<<<dim3(Bq, Uq / 4), 256, 0, stream>>>(hidden, w2_w, w2_b, w1_b, comb);
  k2_score<<<Bq * Tq / 256, 1024, 0, stream>>>(feat, w1hi, w1lo, comb, v_w,
                                               v_b, attn);
  k3_softmax<<<Bq, 256, 0, stream>>>(attn);
  k4_partial<<<dim3(Bq, 8), 256, 0, stream>>>(feat, attn, part);
  k4_reduce<<<Bq, 256, 0, stream>>>(part, ctx);
}

// Round 9
// 90.061 us; speedup vs baseline: 6.3796x; 6.3796x over previous
//
#include <hip/hip_runtime.h>
#include <stdint.h>

// Bahdanau attention: B=64, T=2048, D=256, U=256, all fp32 in/out.
// out = [context (B*D) | attn (B*T)] flat fp32.
#define Bq 64
#define Tq 2048
#define Dq 256
#define Uq 256

typedef __bf16 bf16x8 __attribute__((ext_vector_type(8)));
typedef float f32x4 __attribute__((ext_vector_type(4)));

// A LDS (single bf16 plane, double-buffered): [oct 0..3][row 0..63][16B]
#define ASTR 1040              // 64*16 + 16 pad
#define ABUF (4 * ASTR)        // 4160 per buffer
// B LDS (hi plane only, double-buffered): [oct 0..3][u 0..255][16B]
#define BSTR 4128              // 256*16 + 32 pad
#define BBUF (4 * BSTR)        // 16512 per buffer

// split fp32 into truncated-bf16 hi + bf16(lo) residual (for w1; quasi-exact)
__device__ inline void split2(float a, unsigned short& h, unsigned short& l) {
  unsigned bits = __float_as_uint(a);
  h = (unsigned short)(bits >> 16);
  float hf = __uint_as_float(bits & 0xffff0000u);
  l = (unsigned short)(__float_as_uint(a - hf) >> 16);
}

// fp32 -> bf16 round-to-nearest-even (features; rel err <= 2^-9)
__device__ inline unsigned short rne_bf16(float a) {
  unsigned b = __float_as_uint(a);
  return (unsigned short)((b + 0x7FFFu + ((b >> 16) & 1u)) >> 16);
}

// tanh(x) = 1 - 2/(exp(2x)+1). ~6 VALU ops, saturates correctly.
__device__ inline float fast_tanh(float x) {
  float e = __expf(2.0f * x);
  return 1.0f - 2.0f * __builtin_amdgcn_rcpf(e + 1.0f);
}

// K0: split w1 [U][D] fp32 -> bf16 hi/lo planes, stored OCTET-MAJOR:
// plane[(k>>3)*U*8 + u*8 + (k&7)]
__global__ void k0_split(const float* __restrict__ w1,
                         unsigned short* __restrict__ hi,
                         unsigned short* __restrict__ lo) {
  int idx = blockIdx.x * 256 + threadIdx.x;
  int i = idx * 4;
  int u = i >> 8;
  int k = i & 255;
  float4 v = *reinterpret_cast<const float4*>(&w1[i]);
  ushort4 h, l;
  split2(v.x, h.x, l.x);
  split2(v.y, h.y, l.y);
  split2(v.z, h.z, l.z);
  split2(v.w, h.w, l.w);
  int dst = (k >> 3) * (Uq * 8) + u * 8 + (k & 7);
  *reinterpret_cast<ushort4*>(&hi[dst]) = h;
  *reinterpret_cast<ushort4*>(&lo[dst]) = l;
}

// K1: comb[b][u] = dot(hidden[b], w2_w[u]) + w2_b[u] + w1_b[u]
__global__ void k1_comb(const float* __restrict__ hidden,
                        const float* __restrict__ w2_w,
                        const float* __restrict__ w2_b,
                        const float* __restrict__ w1_b,
                        float* __restrict__ comb) {
  int b = blockIdx.x;
  int wave = threadIdx.x >> 6;
  int lane = threadIdx.x & 63;
  int u = blockIdx.y * 4 + wave;
  const float* h = hidden + b * Dq;
  const float* w = w2_w + u * Dq;
  float sum = 0.f;
#pragma unroll
  for (int i = 0; i < Dq; i += 64) sum += h[lane + i] * w[lane + i];
#pragma unroll
  for (int m = 32; m >= 1; m >>= 1) sum += __shfl_xor(sum, m, 64);
  if (lane == 0) comb[b * Uq + u] = sum + w2_b[u] + w1_b[u];
}

// K2: score[b][t] = v_b + sum_u v_w[u] * tanh( feat[b,t,:]·w1_w[u,:] + comb[b][u] )
// 2-plane MFMA (A=bf16 RNE, B=hi+lo). 256 thr = 4 waves; tile 64t x 256u;
// wave w owns u in [w*64, w*64+64): 4m x 4n fragments of 16x16.
// 1-chunk-ahead pipeline, ONE barrier per chunk:
//   after barrier: issue B-hi DMA(c+1), A(c+1)->regs, B-lo(c+1)->regs;
//   ds_read frags(c); MFMA(c); split+write A(c+1); barrier.
__global__ __launch_bounds__(256) void k2_score(
    const float* __restrict__ feat, const unsigned short* __restrict__ w1hi,
    const unsigned short* __restrict__ w1lo, const float* __restrict__ comb,
    const float* __restrict__ v_w, const float* __restrict__ v_b,
    float* __restrict__ score) {
  __shared__ char sB[2 * BBUF];
  __shared__ char sA[2 * ABUF];
  __shared__ float scp[4 * 64];
  const int b = blockIdx.y;
  const int t0 = blockIdx.x * 64;
  const int tid = threadIdx.x;
  const int w = tid >> 6;
  const int l = tid & 63;
  const int fr = l & 15;
  const int g = l >> 4;

  // A staging role: row = tid>>2 (0..63), oct = tid&3; 8 floats per chunk.
  const int arow = tid >> 2;
  const int aoct = tid & 3;
  const float* aload = feat + ((size_t)(b * Tq + t0 + arow)) * Dq + aoct * 8;
  char* const awr = sA + aoct * ASTR + arow * 16;

  f32x4 acc[4][4] = {};
  float4 pa[2][2];
  bf16x8 bl[2][4];

  auto issueBdma = [&](int c) {
    char* bbase = sB + (c & 1) * BBUF;
#pragma unroll
    for (int q = 0; q < 4; ++q) {
      int d = w * 4 + q;         // 0..15
      int j = d >> 2;            // k-octet in chunk
      int h2 = d & 3;            // u-quarter
      const unsigned short* src =
          w1hi + (size_t)(c * 4 + j) * (Uq * 8) + (h2 * 64 + l) * 8;
      __builtin_amdgcn_global_load_lds(
          (const __attribute__((address_space(1))) unsigned int*)src,
          (__attribute__((address_space(3))) unsigned int*)(bbase + j * BSTR +
                                                            h2 * 1024),
          16, 0, 0);
    }
  };
  auto loadA = [&](int c) {
    pa[c & 1][0] = *reinterpret_cast<const float4*>(aload + c * 32);
    pa[c & 1][1] = *reinterpret_cast<const float4*>(aload + c * 32 + 4);
  };
  auto loadBlo = [&](int c) {
#pragma unroll
    for (int nf = 0; nf < 4; ++nf) {
      size_t off = (size_t)(c * 4 + g) * (Uq * 8) + (w * 64 + nf * 16 + fr) * 8;
      bl[c & 1][nf] = *reinterpret_cast<const bf16x8*>(&w1lo[off]);
    }
  };
  auto writeA = [&](int c) {
    const float4& v0 = pa[c & 1][0];
    const float4& v1 = pa[c & 1][1];
    uint4 H;
    H.x = rne_bf16(v0.x) | ((unsigned)rne_bf16(v0.y) << 16);
    H.y = rne_bf16(v0.z) | ((unsigned)rne_bf16(v0.w) << 16);
    H.z = rne_bf16(v1.x) | ((unsigned)rne_bf16(v1.y) << 16);
    H.w = rne_bf16(v1.z) | ((unsigned)rne_bf16(v1.w) << 16);
    *reinterpret_cast<uint4*>(awr + (c & 1) * ABUF) = H;
  };

  // ---- prologue: stage chunk 0 ----
  issueBdma(0);
  loadA(0);
  loadBlo(0);
  writeA(0);
  __syncthreads();

  // ---- main loop: one barrier per chunk, everything staged 1 chunk ahead ----
#pragma unroll
  for (int c = 0; c < 8; ++c) {
    if (c < 7) {
      issueBdma(c + 1);
      loadA(c + 1);
      loadBlo(c + 1);
    }
    const char* bA = sA + (c & 1) * ABUF;
    const char* bB = sB + (c & 1) * BBUF;
    bf16x8 ah[4], bh[4];
#pragma unroll
    for (int mf = 0; mf < 4; ++mf)
      ah[mf] = *reinterpret_cast<const bf16x8*>(bA + g * ASTR +
                                                (mf * 16 + fr) * 16);
#pragma unroll
    for (int nf = 0; nf < 4; ++nf)
      bh[nf] = *reinterpret_cast<const bf16x8*>(
          bB + g * BSTR + (w * 64 + nf * 16 + fr) * 16);
#pragma unroll
    for (int mf = 0; mf < 4; ++mf) {
#pragma unroll
      for (int nf = 0; nf < 4; ++nf) {
        acc[mf][nf] = __builtin_amdgcn_mfma_f32_16x16x32_bf16(
            ah[mf], bh[nf], acc[mf][nf], 0, 0, 0);
        acc[mf][nf] = __builtin_amdgcn_mfma_f32_16x16x32_bf16(
            ah[mf], bl[c & 1][nf], acc[mf][nf], 0, 0, 0);
      }
    }
    if (c < 7) {
      writeA(c + 1);
      __syncthreads();
    }
  }

  // ---- epilogue: tanh + v-dot. acc[mf][nf][r] is
  // (t_local = mf*16 + g*4 + r, u = w*64 + nf*16 + fr) ----
  float cb[4], vw4[4];
#pragma unroll
  for (int nf = 0; nf < 4; ++nf) {
    int u = w * 64 + nf * 16 + fr;
    cb[nf] = comb[b * Uq + u];
    vw4[nf] = v_w[u];
  }
  float sc[4][4];
#pragma unroll
  for (int mf = 0; mf < 4; ++mf)
#pragma unroll
    for (int r = 0; r < 4; ++r) sc[mf][r] = 0.f;
#pragma unroll
  for (int mf = 0; mf < 4; ++mf)
#pragma unroll
    for (int nf = 0; nf < 4; ++nf)
#pragma unroll
      for (int r = 0; r < 4; ++r)
        sc[mf][r] += vw4[nf] * fast_tanh(acc[mf][nf][r] + cb[nf]);
#pragma unroll
  for (int m = 1; m < 16; m <<= 1)
#pragma unroll
    for (int mf = 0; mf < 4; ++mf)
#pragma unroll
      for (int r = 0; r < 4; ++r) sc[mf][r] += __shfl_xor(sc[mf][r], m, 16);
  __syncthreads();
  if (fr == 0) {
#pragma unroll
    for (int mf = 0; mf < 4; ++mf)
#pragma unroll
      for (int r = 0; r < 4; ++r)
        scp[w * 64 + mf * 16 + g * 4 + r] = sc[mf][r];
  }
  __syncthreads();
  if (tid < 64) {
    float v = scp[tid] + scp[64 + tid] + scp[128 + tid] + scp[192 + tid];
    score[b * Tq + t0 + tid] = v + v_b[0];
  }
}

// K3: softmax over T per batch, in place. 256 threads, 8 values each.
__global__ void k3_softmax(float* __restrict__ s) {
  int b = blockIdx.x;
  int tid = threadIdx.x;
  const int base = b * Tq;
  float v[8];
  float m = -1e30f;
#pragma unroll
  for (int i = 0; i < 8; ++i) {
    v[i] = s[base + tid + 256 * i];
    m = fmaxf(m, v[i]);
  }
#pragma unroll
  for (int mk = 32; mk >= 1; mk >>= 1) m = fmaxf(m, __shfl_xor(m, mk, 64));
  __shared__ float red[4];
  int wv = tid >> 6, ln = tid & 63;
  if (ln == 0) red[wv] = m;
  __syncthreads();
  m = fmaxf(fmaxf(red[0], red[1]), fmaxf(red[2], red[3]));
  __syncthreads();
  float sum = 0.f;
#pragma unroll
  for (int i = 0; i < 8; ++i) {
    v[i] = __expf(v[i] - m);
    sum += v[i];
  }
#pragma unroll
  for (int mk = 32; mk >= 1; mk >>= 1) sum += __shfl_xor(sum, mk, 64);
  if (ln == 0) red[wv] = sum;
  __syncthreads();
  sum = red[0] + red[1] + red[2] + red[3];
  float inv = 1.f / sum;
#pragma unroll
  for (int i = 0; i < 8; ++i) s[base + tid + 256 * i] = v[i] * inv;
}

// K4a: partial context over a 256-t slice
__global__ void k4_partial(const float* __restrict__ feat,
                           const float* __restrict__ attn,
                           float* __restrict__ part) {
  int b = blockIdx.x;
  int ts = blockIdx.y;
  int d = threadIdx.x;
  const int t0 = ts * 256;
  const float* f = feat + ((size_t)(b * Tq + t0)) * Dq + d;
  const float* a = attn + b * Tq + t0;
  float acc = 0.f;
#pragma unroll 8
  for (int t = 0; t < 256; ++t) acc += a[t] * f[(size_t)t * Dq];
  part[(b * 8 + ts) * Dq + d] = acc;
}

// K4b: reduce the 8 partials
__global__ void k4_reduce(const float* __restrict__ part,
                          float* __restrict__ ctx) {
  int b = blockIdx.x;
  int d = threadIdx.x;
  float s = 0.f;
#pragma unroll
  for (int ts = 0; ts < 8; ++ts) s += part[(b * 8 + ts) * Dq + d];
  ctx[b * Dq + d] = s;
}

extern "C" void kernel_launch(void* const* d_in, const int* in_sizes, int n_in,
                              void* d_out, int out_size, void* d_ws,
                              size_t ws_size, hipStream_t stream) {
  const float* feat   = (const float*)d_in[0];
  const float* hidden = (const float*)d_in[1];
  const float* w1_w   = (const float*)d_in[2];
  const float* w1_b   = (const float*)d_in[3];
  const float* w2_w   = (const float*)d_in[4];
  const float* w2_b   = (const float*)d_in[5];
  const float* v_w    = (const float*)d_in[6];
  const float* v_b    = (const float*)d_in[7];

  float* ctx  = (float*)d_out;             // [B][D]
  float* attn = ctx + Bq * Dq;             // [B][T] (score -> softmax in place)
  float* comb = (float*)d_ws;              // [B][U]        64 KB
  float* part = comb + Bq * Uq;            // [B][8][D]     512 KB
  unsigned short* w1hi = (unsigned short*)(part + Bq * 8 * Dq);  // 128 KB
  unsigned short* w1lo = w1hi + Uq * Dq;                          // 128 KB

  k0_split<<<Uq * Dq / 1024, 256, 0, stream>>>(w1_w, w1hi, w1lo);
  k1_comb<<<dim3(Bq, Uq / 4), 256, 0, stream>>>(hidden, w2_w, w2_b, w1_b, comb);
  k2_score<<<dim3(Tq / 64, Bq), 256, 0, stream>>>(feat, w1hi, w1lo, comb, v_w,
                                                  v_b, attn);
  k3_softmax<<<Bq, 256, 0, stream>>>(attn);
  k4_partial<<<dim3(Bq, 8), 256, 0, stream>>>(feat, attn, part);
  k4_reduce<<<Bq, 256, 0, stream>>>(part, ctx);
}